// Round 1
// baseline (189.484 us; speedup 1.0000x reference)
//
#include <hip/hip_runtime.h>
#include <math.h>

#define N 8192
#define H 64
#define B 8
#define MAXDEG 128
#define ROWS 8

// ---- workspace layout (bytes) ----
// zeroed region: [0, ZERO_END)
#define OFF_MASK  0ULL                      // 8192*8192/8 = 8,388,608
#define OFF_CNT   8388608ULL                // 8192 u32 = 32,768
#define OFF_WACC  8421376ULL                // 512 f32 = 2048
#define OFF_PACC  8423424ULL                // 512 f32 = 2048
#define ZERO_END  8425472ULL
#define OFF_COLS  8425472ULL                // 8192*128 u32 = 4,194,304
#define OFF_DIS   12619776ULL               // 8192 f32 = 32,768
#define OFF_TGT   12652544ULL               // 512 f32 = 2048
#define OFF_HPS   12654592ULL               // 8*8192*64 f32 = 67,108,864
// total ~79.8 MB

// K1: dedup edges via bitmask; count distinct out-degree; build padded col lists
__global__ __launch_bounds__(256) void k_edges(const int* __restrict__ ei, int nE,
                                               unsigned* __restrict__ bits,
                                               unsigned* __restrict__ cnt,
                                               unsigned* __restrict__ cols) {
    int e = blockIdx.x * blockDim.x + threadIdx.x;
    if (e >= nE) return;
    int r = ei[e];
    int c = ei[nE + e];
    unsigned bitidx = (unsigned)r * (unsigned)N + (unsigned)c;   // < 2^26
    unsigned word = bitidx >> 5;
    unsigned bit  = 1u << (bitidx & 31u);
    unsigned old = atomicOr(&bits[word], bit);
    if (!(old & bit)) {
        unsigned k = atomicAdd(&cnt[r], 1u);
        if (k < MAXDEG) cols[r * MAXDEG + k] = (unsigned)c;
    }
}

// K2: dis[n] = (deg)^(-1/2), deg = distinct_out + 1 (eye)
__global__ __launch_bounds__(256) void k_dis(const unsigned* __restrict__ cnt,
                                             float* __restrict__ dis) {
    int n = blockIdx.x * blockDim.x + threadIdx.x;
    if (n < N) dis[n] = rsqrtf((float)(cnt[n] + 1u));
}

// K3: hp_s[b,m,:] = dis[m] * ((node_emb[m] + x@W_sp^T + b_sp) @ W_g^T)
__global__ __launch_bounds__(256) void k_hproj(const float* __restrict__ x,
                                               const float* __restrict__ node_emb,
                                               const float* __restrict__ W_sp,
                                               const float* __restrict__ b_sp,
                                               const float* __restrict__ W_g,
                                               const float* __restrict__ dis,
                                               float* __restrict__ hps) {
    __shared__ float wg[H * (H + 1)];   // padded: bank = (l+k)%32, 2-way (free)
    __shared__ float hv[4][H];
    int tid = threadIdx.x;
    for (int i = tid; i < H * H; i += 256) {
        int row = i >> 6, col = i & 63;
        wg[row * (H + 1) + col] = W_g[i];
    }
    __syncthreads();
    int w = tid >> 6;
    int l = tid & 63;
    int wid = blockIdx.x * 4 + w;       // global (b,m) wave id
    int b = wid >> 13;
    int m = wid & (N - 1);
    float x0 = x[(b * N + m) * 2 + 0];
    float x1 = x[(b * N + m) * 2 + 1];
    float h = node_emb[m * H + l] + x0 * W_sp[l * 2 + 0] + x1 * W_sp[l * 2 + 1] + b_sp[l];
    hv[w][l] = h;
    __syncthreads();
    float acc = 0.f;
#pragma unroll
    for (int k = 0; k < H; ++k)
        acc = fmaf(wg[l * (H + 1) + k], hv[w][k], acc);
    hps[(b * N + m) * H + l] = dis[m] * acc;
}

// K4: fused sparse SpMM + relu + all row-reductions (never materialize z)
__global__ __launch_bounds__(512) void k_spmm(const float* __restrict__ hps,
                                              const unsigned* __restrict__ cnt,
                                              const unsigned* __restrict__ cols,
                                              const float* __restrict__ dis,
                                              const float* __restrict__ b_g,
                                              const float* __restrict__ x,
                                              const float* __restrict__ pmask,
                                              const int* __restrict__ target,
                                              float* __restrict__ wacc,
                                              float* __restrict__ pacc,
                                              float* __restrict__ tgt) {
    const int tid = threadIdx.x;
    const int b = tid >> 6, h = tid & 63;
    const int row0 = blockIdx.x * ROWS;
    const float bg = b_g[h];
    const int tgt_b = target[b];
    float wloc = 0.f, ploc = 0.f;
    for (int i = 0; i < ROWS; ++i) {
        int r = row0 + i;
        int kc = (int)min(cnt[r], (unsigned)MAXDEG);
        float acc = hps[(b * N + r) * H + h];      // eye term (pre-scaled by dis[r])
        const unsigned* cl = &cols[r * MAXDEG];
#pragma unroll 4
        for (int k = 0; k < kc; ++k) {
            int c = (int)cl[k];
            acc += hps[(b * N + c) * H + h];
        }
        float z = fmaxf(fmaf(dis[r], acc, bg), 0.f);
        float sc = x[(b * N + r) * 2 + 1];
        float mk = pmask[b * N + r];
        wloc = fmaf(z, sc, wloc);
        // softplus(z) = z + log1p(exp(-z)), stable for z >= 0
        ploc = fmaf(z + log1pf(__expf(-z)), mk, ploc);
        if (r == tgt_b) tgt[b * H + h] = z;
    }
    atomicAdd(&wacc[b * H + h], wloc);
    atomicAdd(&pacc[b * H + h], ploc);
}

// K5: per-batch final dots + sigmoid
__global__ __launch_bounds__(512) void k_final(const float* __restrict__ x,
                                               const float* __restrict__ wacc,
                                               const float* __restrict__ pacc,
                                               const float* __restrict__ tgt,
                                               const float* __restrict__ W_d,
                                               const float* __restrict__ b_d,
                                               const float* __restrict__ W_a,
                                               const float* __restrict__ b_a,
                                               const float* __restrict__ prereq_w,
                                               float* __restrict__ out) {
    __shared__ float nls[B];
    int tid = threadIdx.x, b = tid >> 6, h = tid & 63;
    // n_learned[b] = max(sum_n x[b,n,0], 1)
    float s = 0.f;
    for (int i = h; i < N; i += 64) s += x[(b * N + i) * 2 + 0];
    for (int off = 32; off; off >>= 1) s += __shfl_down(s, off, 64);
    if (h == 0) nls[b] = fmaxf(s, 1.0f);
    __syncthreads();
    float nl = nls[b];
    float ap = (wacc[b * H + h] / nl) * W_a[h];
    float dp = tgt[b * H + h] * W_d[h];
    float pp = pacc[b * H + h];
    for (int off = 32; off; off >>= 1) {
        ap += __shfl_down(ap, off, 64);
        dp += __shfl_down(dp, off, 64);
        pp += __shfl_down(pp, off, 64);
    }
    if (h == 0) {
        float ability    = ap + b_a[0];
        float difficulty = dp + b_d[0];
        float preq       = fabsf(prereq_w[0]) * (pp * (1.0f / (float)H));
        float gap  = ability - difficulty + preq;
        float prob = 1.0f / (1.0f + __expf(-gap));
        out[b]     = prob;
        out[B + b] = gap;
    }
}

extern "C" void kernel_launch(void* const* d_in, const int* in_sizes, int n_in,
                              void* d_out, int out_size, void* d_ws, size_t ws_size,
                              hipStream_t stream) {
    const float* x         = (const float*)d_in[0];
    const int*   ei        = (const int*)d_in[1];
    const int*   target    = (const int*)d_in[2];
    const float* pmask     = (const float*)d_in[3];
    const float* node_emb  = (const float*)d_in[4];
    const float* W_sp      = (const float*)d_in[5];
    const float* b_sp      = (const float*)d_in[6];
    const float* W_g       = (const float*)d_in[7];
    const float* b_g       = (const float*)d_in[8];
    const float* W_d       = (const float*)d_in[9];
    const float* b_d       = (const float*)d_in[10];
    const float* W_a       = (const float*)d_in[11];
    const float* b_a       = (const float*)d_in[12];
    const float* prereq_w  = (const float*)d_in[13];

    const int nE = in_sizes[1] / 2;

    char* ws = (char*)d_ws;
    unsigned* bits = (unsigned*)(ws + OFF_MASK);
    unsigned* cnt  = (unsigned*)(ws + OFF_CNT);
    float*    wacc = (float*)(ws + OFF_WACC);
    float*    pacc = (float*)(ws + OFF_PACC);
    unsigned* cols = (unsigned*)(ws + OFF_COLS);
    float*    dis  = (float*)(ws + OFF_DIS);
    float*    tgt  = (float*)(ws + OFF_TGT);
    float*    hps  = (float*)(ws + OFF_HPS);

    // zero bitmask + counts + accumulators (ws is poisoned 0xAA, not re-poisoned
    // between replays — so we must zero every call)
    hipMemsetAsync(ws, 0, (size_t)ZERO_END, stream);

    k_edges<<<(nE + 255) / 256, 256, 0, stream>>>(ei, nE, bits, cnt, cols);
    k_dis<<<N / 256, 256, 0, stream>>>(cnt, dis);
    k_hproj<<<(B * N) / 4, 256, 0, stream>>>(x, node_emb, W_sp, b_sp, W_g, dis, hps);
    k_spmm<<<N / ROWS, 512, 0, stream>>>(hps, cnt, cols, dis, b_g, x, pmask, target,
                                         wacc, pacc, tgt);
    k_final<<<1, 512, 0, stream>>>(x, wacc, pacc, tgt, W_d, b_d, W_a, b_a,
                                   prereq_w, (float*)d_out);
}

// Round 2
// 150.233 us; speedup vs baseline: 1.2613x; 1.2613x over previous
//
#include <hip/hip_runtime.h>
#include <hip/hip_bf16.h>
#include <math.h>

#define N 8192
#define H 64
#define B 8
#define MAXDEG 128
#define ROWS 8

// ---- workspace layout (bytes) ----
// zeroed region: [0, ZERO_END)
#define OFF_MASK  0ULL                      // 8192*8192/8 = 8,388,608
#define OFF_CNT   8388608ULL                // 8192 u32 = 32,768
#define OFF_WACC  8421376ULL                // 512 f32 = 2048
#define OFF_PACC  8423424ULL                // 512 f32 = 2048
#define OFF_NL    8425472ULL                // 8 f32 = 32
#define ZERO_END  8425504ULL
#define OFF_COLS  8425504ULL                // 8192*128 u32 = 4,194,304
#define OFF_TGT   12619808ULL               // 512 f32 = 2048
#define OFF_HPS   12621856ULL               // 8192*8*64 bf16 = 8,388,608
// total ~21 MB

// K1: dedup edges via bitmask; count distinct out-degree; build padded col lists
__global__ __launch_bounds__(256) void k_edges(const int* __restrict__ ei, int nE,
                                               unsigned* __restrict__ bits,
                                               unsigned* __restrict__ cnt,
                                               unsigned* __restrict__ cols) {
    int e = blockIdx.x * blockDim.x + threadIdx.x;
    if (e >= nE) return;
    int r = ei[e];
    int c = ei[nE + e];
    unsigned bitidx = (unsigned)r * (unsigned)N + (unsigned)c;   // < 2^26
    unsigned word = bitidx >> 5;
    unsigned bit  = 1u << (bitidx & 31u);
    unsigned old = atomicOr(&bits[word], bit);
    if (!(old & bit)) {
        unsigned k = atomicAdd(&cnt[r], 1u);
        if (k < MAXDEG) cols[r * MAXDEG + k] = (unsigned)c;
    }
}

// K2: hps[m][b][h] (bf16) = dis[m] * ((node_emb[m] + x@W_sp^T + b_sp) @ W_g^T)
// dis computed inline from cnt. 4 waves/block, 4 (b,m) tasks per wave.
__global__ __launch_bounds__(256) void k_hproj(const float* __restrict__ x,
                                               const float* __restrict__ node_emb,
                                               const float* __restrict__ W_sp,
                                               const float* __restrict__ b_sp,
                                               const float* __restrict__ W_g,
                                               const unsigned* __restrict__ cnt,
                                               __hip_bfloat16* __restrict__ hps) {
    __shared__ float wg[H * (H + 1)];   // padded
    __shared__ float hv[4][H];
    int tid = threadIdx.x;
    for (int i = tid; i < H * H; i += 256) {
        wg[(i >> 6) * (H + 1) + (i & 63)] = W_g[i];
    }
    __syncthreads();
    int w = tid >> 6;
    int l = tid & 63;
    float wsp0 = W_sp[l * 2 + 0], wsp1 = W_sp[l * 2 + 1], bsp = b_sp[l];
    for (int it = 0; it < 4; ++it) {
        int wid = blockIdx.x * 16 + it * 4 + w;
        int b = wid >> 13;
        int m = wid & (N - 1);
        float x0 = x[(b * N + m) * 2 + 0];
        float x1 = x[(b * N + m) * 2 + 1];
        // wave-private LDS row; same-wave write->read is lockstep-ordered
        hv[w][l] = node_emb[m * H + l] + x0 * wsp0 + x1 * wsp1 + bsp;
        float acc = 0.f;
#pragma unroll
        for (int k = 0; k < H; ++k)
            acc = fmaf(wg[l * (H + 1) + k], hv[w][k], acc);
        float disv = rsqrtf((float)(cnt[m] + 1u));
        hps[(m * B + b) * H + l] = __float2bfloat16(disv * acc);
    }
}

__device__ __forceinline__ float bf_lo(unsigned v) {
    return __uint_as_float(v << 16);
}
__device__ __forceinline__ float bf_hi(unsigned v) {
    return __uint_as_float(v & 0xffff0000u);
}

// K3: fused sparse SpMM + relu + all row-reductions (never materialize z)
// 256 threads = 8 batches x 32 h-pairs; gathers are 1KB contiguous per column.
__global__ __launch_bounds__(256) void k_spmm(const unsigned* __restrict__ hps,
                                              const unsigned* __restrict__ cnt,
                                              const unsigned* __restrict__ cols,
                                              const float* __restrict__ b_g,
                                              const float* __restrict__ x,
                                              const float* __restrict__ pmask,
                                              const int* __restrict__ target,
                                              float* __restrict__ wacc,
                                              float* __restrict__ pacc,
                                              float* __restrict__ nlacc,
                                              float* __restrict__ tgt) {
    const int tid = threadIdx.x;
    const int b = tid >> 5, hp = tid & 31;
    const int row0 = blockIdx.x * ROWS;
    const float bg0 = b_g[2 * hp], bg1 = b_g[2 * hp + 1];
    const int tgt_b = target[b];
    float w0 = 0.f, w1 = 0.f, p0 = 0.f, p1 = 0.f, nll = 0.f;
    for (int i = 0; i < ROWS; ++i) {
        int r = row0 + i;
        int kc = (int)min(cnt[r], (unsigned)MAXDEG);
        const unsigned* cl = &cols[r * MAXDEG];     // block-uniform -> s_load
        unsigned e = hps[(r * B + b) * 32 + hp];    // eye term (pre-scaled)
        float a0 = bf_lo(e), a1 = bf_hi(e);
#pragma unroll 4
        for (int k = 0; k < kc; ++k) {
            int c = (int)cl[k];
            unsigned v = hps[(c * B + b) * 32 + hp];
            a0 += bf_lo(v);
            a1 += bf_hi(v);
        }
        float disv = rsqrtf((float)(cnt[r] + 1u));
        float z0 = fmaxf(fmaf(disv, a0, bg0), 0.f);
        float z1 = fmaxf(fmaf(disv, a1, bg1), 0.f);
        float2 xv = ((const float2*)x)[b * N + r];
        float mk = pmask[b * N + r];
        w0 = fmaf(z0, xv.y, w0);
        w1 = fmaf(z1, xv.y, w1);
        // softplus(z) = z + log(1+exp(-z)), stable for z >= 0
        p0 = fmaf(z0 + __logf(1.f + __expf(-z0)), mk, p0);
        p1 = fmaf(z1 + __logf(1.f + __expf(-z1)), mk, p1);
        if (hp == 0) nll += xv.x;                   // n_learned partial
        if (r == tgt_b) {
            tgt[b * H + 2 * hp]     = z0;
            tgt[b * H + 2 * hp + 1] = z1;
        }
    }
    atomicAdd(&wacc[b * H + 2 * hp], w0);
    atomicAdd(&wacc[b * H + 2 * hp + 1], w1);
    atomicAdd(&pacc[b * H + 2 * hp], p0);
    atomicAdd(&pacc[b * H + 2 * hp + 1], p1);
    if (hp == 0) atomicAdd(&nlacc[b], nll);
}

// K4: per-batch final dots + sigmoid (tiny)
__global__ __launch_bounds__(512) void k_final(const float* __restrict__ wacc,
                                               const float* __restrict__ pacc,
                                               const float* __restrict__ nlacc,
                                               const float* __restrict__ tgt,
                                               const float* __restrict__ W_d,
                                               const float* __restrict__ b_d,
                                               const float* __restrict__ W_a,
                                               const float* __restrict__ b_a,
                                               const float* __restrict__ prereq_w,
                                               float* __restrict__ out) {
    int tid = threadIdx.x, b = tid >> 6, h = tid & 63;
    float nl = fmaxf(nlacc[b], 1.0f);
    float ap = (wacc[b * H + h] / nl) * W_a[h];
    float dp = tgt[b * H + h] * W_d[h];
    float pp = pacc[b * H + h];
    for (int off = 32; off; off >>= 1) {
        ap += __shfl_down(ap, off, 64);
        dp += __shfl_down(dp, off, 64);
        pp += __shfl_down(pp, off, 64);
    }
    if (h == 0) {
        float ability    = ap + b_a[0];
        float difficulty = dp + b_d[0];
        float preq       = fabsf(prereq_w[0]) * (pp * (1.0f / (float)H));
        float gap  = ability - difficulty + preq;
        float prob = 1.0f / (1.0f + __expf(-gap));
        out[b]     = prob;
        out[B + b] = gap;
    }
}

extern "C" void kernel_launch(void* const* d_in, const int* in_sizes, int n_in,
                              void* d_out, int out_size, void* d_ws, size_t ws_size,
                              hipStream_t stream) {
    const float* x         = (const float*)d_in[0];
    const int*   ei        = (const int*)d_in[1];
    const int*   target    = (const int*)d_in[2];
    const float* pmask     = (const float*)d_in[3];
    const float* node_emb  = (const float*)d_in[4];
    const float* W_sp      = (const float*)d_in[5];
    const float* b_sp      = (const float*)d_in[6];
    const float* W_g       = (const float*)d_in[7];
    const float* b_g       = (const float*)d_in[8];
    const float* W_d       = (const float*)d_in[9];
    const float* b_d       = (const float*)d_in[10];
    const float* W_a       = (const float*)d_in[11];
    const float* b_a       = (const float*)d_in[12];
    const float* prereq_w  = (const float*)d_in[13];

    const int nE = in_sizes[1] / 2;

    char* ws = (char*)d_ws;
    unsigned*        bits = (unsigned*)(ws + OFF_MASK);
    unsigned*        cnt  = (unsigned*)(ws + OFF_CNT);
    float*           wacc = (float*)(ws + OFF_WACC);
    float*           pacc = (float*)(ws + OFF_PACC);
    float*           nlac = (float*)(ws + OFF_NL);
    unsigned*        cols = (unsigned*)(ws + OFF_COLS);
    float*           tgt  = (float*)(ws + OFF_TGT);
    __hip_bfloat16*  hps  = (__hip_bfloat16*)(ws + OFF_HPS);

    // must zero every call: ws is poisoned once, never re-poisoned
    hipMemsetAsync(ws, 0, (size_t)ZERO_END, stream);

    k_edges<<<(nE + 255) / 256, 256, 0, stream>>>(ei, nE, bits, cnt, cols);
    k_hproj<<<(B * N) / 16, 256, 0, stream>>>(x, node_emb, W_sp, b_sp, W_g, cnt, hps);
    k_spmm<<<N / ROWS, 256, 0, stream>>>((const unsigned*)hps, cnt, cols, b_g, x,
                                         pmask, target, wacc, pacc, nlac, tgt);
    k_final<<<1, 512, 0, stream>>>(wacc, pacc, nlac, tgt, W_d, b_d, W_a, b_a,
                                   prereq_w, (float*)d_out);
}

// Round 3
// 88.651 us; speedup vs baseline: 2.1374x; 1.6946x over previous
//
#include <hip/hip_runtime.h>
#include <hip/hip_bf16.h>
#include <math.h>

#define N 8192
#define H 64
#define B 8
#define MAXDEG 128
#define REPS 32
#define RPW 2            // rows per wave in k_spmm

// ---- workspace layout (bytes) ----
// zeroed every call: [0, ZERO_END)
#define OFF_MASK 0ULL            // 8192*8192/8 = 8,388,608
#define OFF_CNT  8388608ULL      // 8192 u32
#define OFF_WR   8421376ULL      // REPS*8*64 f32 = 65536
#define OFF_PR   8486912ULL      // 65536
#define OFF_NL   8552448ULL      // 8 f32
#define ZERO_END 8552480ULL
// not zeroed:
#define OFF_COLS 8552704ULL      // 8192*128 u16 = 2,097,152
#define OFF_TGT  10649856ULL     // 512 f32
#define OFF_UV   10651904ULL     // 3*64 f32 (u0,u1,ub)
#define OFF_XD   10652672ULL     // 8192*32 f32 = 1,048,576
#define OFF_PD   11701248ULL     // 8192*64 bf16 = 1,048,576
// end ~12.75 MB

__device__ __forceinline__ float bf2f(unsigned short u) {
    return __uint_as_float(((unsigned)u) << 16);
}

// K1: dedup edges via N^2 bitmask; distinct out-degree; padded u16 col lists
__global__ __launch_bounds__(256) void k_edges(const int* __restrict__ ei, int nE,
                                               unsigned* __restrict__ bits,
                                               unsigned* __restrict__ cnt,
                                               unsigned short* __restrict__ cols) {
    int e = blockIdx.x * blockDim.x + threadIdx.x;
    if (e >= nE) return;
    int r = ei[e];
    int c = ei[nE + e];
    unsigned bitidx = (unsigned)r * (unsigned)N + (unsigned)c;
    unsigned old = atomicOr(&bits[bitidx >> 5], 1u << (bitidx & 31u));
    if (!(old & (1u << (bitidx & 31u)))) {
        unsigned k = atomicAdd(&cnt[r], 1u);
        if (k < MAXDEG) cols[r * MAXDEG + k] = (unsigned short)c;
    }
}

// K2: Pd[m][l] = dis_m * (W_g @ ne[m])_l  (bf16);  uvec = {W_g@Wsp0, W_g@Wsp1, W_g@b_sp}
__global__ __launch_bounds__(256) void k_prep(const float* __restrict__ ne,
                                              const float* __restrict__ W_g,
                                              const float* __restrict__ W_sp,
                                              const float* __restrict__ b_sp,
                                              const unsigned* __restrict__ cnt,
                                              __hip_bfloat16* __restrict__ Pd,
                                              float* __restrict__ uvec) {
    __shared__ float wg[H * (H + 1)];
    int tid = threadIdx.x;
    for (int i = tid; i < H * H; i += 256)
        wg[(i >> 6) * (H + 1) + (i & 63)] = W_g[i];
    __syncthreads();
    const int l = tid & 63, w = tid >> 6;
    float wr[H];
#pragma unroll
    for (int k = 0; k < H; ++k) wr[k] = wg[l * (H + 1) + k];   // W_g row l, 2-way bank (free)

    if (blockIdx.x == 0 && w == 0) {
        float v0 = W_sp[l * 2 + 0], v1 = W_sp[l * 2 + 1], vb = b_sp[l];  // lane = k
        float a0 = 0.f, a1 = 0.f, a2 = 0.f;
#pragma unroll
        for (int k = 0; k < H; ++k) {
            a0 = fmaf(wr[k], __shfl(v0, k, 64), a0);
            a1 = fmaf(wr[k], __shfl(v1, k, 64), a1);
            a2 = fmaf(wr[k], __shfl(vb, k, 64), a2);
        }
        uvec[l] = a0; uvec[64 + l] = a1; uvec[128 + l] = a2;
    }

#pragma unroll
    for (int it = 0; it < 4; ++it) {
        int m = (blockIdx.x * 4 + w) * 4 + it;
        float nev = ne[m * H + l];                 // lane = k index
        float c0 = 0.f, c1 = 0.f, c2 = 0.f, c3 = 0.f;
#pragma unroll
        for (int k = 0; k < H; k += 4) {
            c0 = fmaf(wr[k + 0], __shfl(nev, k + 0, 64), c0);
            c1 = fmaf(wr[k + 1], __shfl(nev, k + 1, 64), c1);
            c2 = fmaf(wr[k + 2], __shfl(nev, k + 2, 64), c2);
            c3 = fmaf(wr[k + 3], __shfl(nev, k + 3, 64), c3);
        }
        float dis = rsqrtf((float)(cnt[m] + 1u));
        Pd[m * H + l] = __float2bfloat16(dis * ((c0 + c1) + (c2 + c3)));
    }
}

// K3: xd[m][0..7]=dis*x0_b, [8..15]=dis*x1_b, [16]=dis, [17..24]=pmask_b, rest 0.
// Also accumulates n_learned partials.
__global__ __launch_bounds__(256) void k_xd(const float* __restrict__ x,
                                            const float* __restrict__ pmask,
                                            const unsigned* __restrict__ cnt,
                                            float* __restrict__ xd,
                                            float* __restrict__ nlacc) {
    int m = blockIdx.x * blockDim.x + threadIdx.x;
    float dis = rsqrtf((float)(cnt[m] + 1u));
    float row[32];
#pragma unroll
    for (int j = 0; j < 32; ++j) row[j] = 0.f;
    row[16] = dis;
#pragma unroll
    for (int b = 0; b < B; ++b) {
        float2 xv = ((const float2*)x)[b * N + m];
        row[b]      = dis * xv.x;
        row[8 + b]  = dis * xv.y;
        row[17 + b] = pmask[b * N + m];
        float s = xv.x;
        for (int off = 32; off; off >>= 1) s += __shfl_down(s, off, 64);
        if ((threadIdx.x & 63) == 0) atomicAdd(&nlacc[b], s);
    }
    float4* dst = (float4*)&xd[m * 32];
#pragma unroll
    for (int j = 0; j < 8; ++j)
        dst[j] = make_float4(row[4 * j], row[4 * j + 1], row[4 * j + 2], row[4 * j + 3]);
}

// K4: batch-collapsed sparse row-gather + z reconstruction + all reductions.
// Wave-per-row; lane l owns feature l. No LDS, no barriers.
__global__ __launch_bounds__(256) void k_spmm(const unsigned short* __restrict__ Pd,
                                              const float* __restrict__ xd,
                                              const unsigned* __restrict__ cnt,
                                              const unsigned short* __restrict__ cols,
                                              const float* __restrict__ uvec,
                                              const float* __restrict__ b_g,
                                              const int* __restrict__ target,
                                              float* __restrict__ wr_,
                                              float* __restrict__ pr_,
                                              float* __restrict__ tgt) {
    const int lane = threadIdx.x & 63;
    const int wv = threadIdx.x >> 6;
    const int wid = blockIdx.x * 4 + wv;
    const float u0 = uvec[lane], u1 = uvec[64 + lane], ub = uvec[128 + lane];
    const float bg = b_g[lane];
    int tg[B];
#pragma unroll
    for (int b = 0; b < B; ++b) tg[b] = target[b];
    float wa[B], pa[B];
#pragma unroll
    for (int b = 0; b < B; ++b) { wa[b] = 0.f; pa[b] = 0.f; }

    for (int i = 0; i < RPW; ++i) {
        const int r = wid * RPW + i;
        // eye-term init (row r itself)
        float rloc = xd[r * 32 + (lane & 31)];
        float sp = bf2f(Pd[r * H + lane]);
        float sx = rloc;
        const int kc = min((int)cnt[r], MAXDEG);
        const unsigned short* cl = &cols[r * MAXDEG];
#pragma unroll 4
        for (int k = 0; k < kc; ++k) {
            int c = (int)cl[k];
            sp += bf2f(Pd[c * H + lane]);
            sx += xd[c * 32 + (lane & 31)];
        }
        const float dis_r = __shfl(rloc, 16, 64);
        const float rdis = 1.0f / dis_r;
        const float sd = __shfl(sx, 16, 64);
        const float base = fmaf(sd, ub, sp);
#pragma unroll
        for (int b = 0; b < B; ++b) {
            float sx0 = __shfl(sx, b, 64);
            float sx1 = __shfl(sx, 8 + b, 64);
            float sc  = __shfl(rloc, 8 + b, 64) * rdis;   // score = x1
            float mk  = __shfl(rloc, 17 + b, 64);
            float v = fmaf(sx0, u0, fmaf(sx1, u1, base));
            float z = fmaxf(fmaf(dis_r, v, bg), 0.f);
            wa[b] = fmaf(z, sc, wa[b]);
            float spl = z + __logf(1.f + __expf(-z));     // softplus, z>=0 stable
            pa[b] = fmaf(spl, mk, pa[b]);
            if (r == tg[b]) tgt[b * H + lane] = z;
        }
    }
    const int rep = wid & (REPS - 1);
#pragma unroll
    for (int b = 0; b < B; ++b) {
        atomicAdd(&wr_[(rep * B + b) * H + lane], wa[b]);
        atomicAdd(&pr_[(rep * B + b) * H + lane], pa[b]);
    }
}

// K5: reduce replicas, per-batch dots, sigmoid
__global__ __launch_bounds__(512) void k_final(const float* __restrict__ wr_,
                                               const float* __restrict__ pr_,
                                               const float* __restrict__ nlacc,
                                               const float* __restrict__ tgt,
                                               const float* __restrict__ W_d,
                                               const float* __restrict__ b_d,
                                               const float* __restrict__ W_a,
                                               const float* __restrict__ b_a,
                                               const float* __restrict__ prereq_w,
                                               float* __restrict__ out) {
    int tid = threadIdx.x, b = tid >> 6, h = tid & 63;
    float ws = 0.f, ps = 0.f;
#pragma unroll 8
    for (int rep = 0; rep < REPS; ++rep) {
        ws += wr_[(rep * B + b) * H + h];
        ps += pr_[(rep * B + b) * H + h];
    }
    float nl = fmaxf(nlacc[b], 1.0f);
    float ap = (ws / nl) * W_a[h];
    float dp = tgt[b * H + h] * W_d[h];
    float pp = ps;
    for (int off = 32; off; off >>= 1) {
        ap += __shfl_down(ap, off, 64);
        dp += __shfl_down(dp, off, 64);
        pp += __shfl_down(pp, off, 64);
    }
    if (h == 0) {
        float ability    = ap + b_a[0];
        float difficulty = dp + b_d[0];
        float preq       = fabsf(prereq_w[0]) * (pp * (1.0f / (float)H));
        float gap  = ability - difficulty + preq;
        float prob = 1.0f / (1.0f + __expf(-gap));
        out[b]     = prob;
        out[B + b] = gap;
    }
}

extern "C" void kernel_launch(void* const* d_in, const int* in_sizes, int n_in,
                              void* d_out, int out_size, void* d_ws, size_t ws_size,
                              hipStream_t stream) {
    const float* x        = (const float*)d_in[0];
    const int*   ei       = (const int*)d_in[1];
    const int*   target   = (const int*)d_in[2];
    const float* pmask    = (const float*)d_in[3];
    const float* node_emb = (const float*)d_in[4];
    const float* W_sp     = (const float*)d_in[5];
    const float* b_sp     = (const float*)d_in[6];
    const float* W_g      = (const float*)d_in[7];
    const float* b_g      = (const float*)d_in[8];
    const float* W_d      = (const float*)d_in[9];
    const float* b_d      = (const float*)d_in[10];
    const float* W_a      = (const float*)d_in[11];
    const float* b_a      = (const float*)d_in[12];
    const float* prereq_w = (const float*)d_in[13];

    const int nE = in_sizes[1] / 2;

    char* ws = (char*)d_ws;
    unsigned*        bits = (unsigned*)(ws + OFF_MASK);
    unsigned*        cnt  = (unsigned*)(ws + OFF_CNT);
    float*           wr_  = (float*)(ws + OFF_WR);
    float*           pr_  = (float*)(ws + OFF_PR);
    float*           nlac = (float*)(ws + OFF_NL);
    unsigned short*  cols = (unsigned short*)(ws + OFF_COLS);
    float*           tgt  = (float*)(ws + OFF_TGT);
    float*           uvec = (float*)(ws + OFF_UV);
    float*           xd   = (float*)(ws + OFF_XD);
    __hip_bfloat16*  Pd   = (__hip_bfloat16*)(ws + OFF_PD);

    // ws poisoned 0xAA once, never re-poisoned between replays -> zero every call
    hipMemsetAsync(ws, 0, (size_t)ZERO_END, stream);

    k_edges<<<(nE + 255) / 256, 256, 0, stream>>>(ei, nE, bits, cnt, cols);
    k_prep<<<N / 16, 256, 0, stream>>>(node_emb, W_g, W_sp, b_sp, cnt, Pd, uvec);
    k_xd<<<N / 256, 256, 0, stream>>>(x, pmask, cnt, xd, nlac);
    k_spmm<<<N / (4 * RPW), 256, 0, stream>>>((const unsigned short*)Pd, xd, cnt, cols,
                                              uvec, b_g, target, wr_, pr_, tgt);
    k_final<<<1, 512, 0, stream>>>(wr_, pr_, nlac, tgt, W_d, b_d, W_a, b_a,
                                   prereq_w, (float*)d_out);
}

// Round 4
// 81.469 us; speedup vs baseline: 2.3259x; 1.0882x over previous
//
#include <hip/hip_runtime.h>
#include <hip/hip_bf16.h>
#include <math.h>

#define N 8192
#define H 64
#define B 8
#define MAXDEG 128
#define REPS 32
#define RPW 2            // rows per wave in k_spmm

// ---- workspace layout (bytes) ----
// zeroed every call: [0, ZERO_END)
#define OFF_CNT  0ULL            // 8192 u32 = 32768
#define OFF_WR   32768ULL        // REPS*8*64 f32 = 65536
#define OFF_PR   98304ULL        // 65536
#define OFF_NL   163840ULL       // 8 f32 (+pad)
#define ZERO_END 163904ULL       // /16 = 10244
// not zeroed:
#define OFF_COLS 163904ULL       // 8192*128 u16 = 2,097,152
#define OFF_TGT  2261056ULL      // 512 f32
#define OFF_UV   2263104ULL      // 3*64 f32
#define OFF_XD   2263872ULL      // 8192*32 f32 = 1,048,576 (16B aligned)
#define OFF_PD   3312448ULL      // 8192*64 bf16 = 1,048,576
// end ~4.4 MB

__device__ __forceinline__ float bf2f(unsigned short u) {
    return __uint_as_float(((unsigned)u) << 16);
}

// K0: zero the 160KB accumulator region (runtime fillBuffer was ~40us!)
__global__ __launch_bounds__(256) void k_zero(float4* __restrict__ p) {
    unsigned i = blockIdx.x * 256u + threadIdx.x;
    if (i < (unsigned)(ZERO_END / 16))
        p[i] = make_float4(0.f, 0.f, 0.f, 0.f);
}

// K1: append edges (no dedup here)
__global__ __launch_bounds__(256) void k_edges(const int* __restrict__ ei, int nE,
                                               unsigned* __restrict__ cnt,
                                               unsigned short* __restrict__ cols) {
    int e = blockIdx.x * blockDim.x + threadIdx.x;
    if (e >= nE) return;
    int r = ei[e];
    int c = ei[nE + e];
    unsigned k = atomicAdd(&cnt[r], 1u);
    if (k < MAXDEG) cols[r * MAXDEG + k] = (unsigned short)c;
}

// K1b: per-row in-list dedup + compaction; cnt[r] <- distinct count.
// One wave per row; row list staged in LDS; ballot/popcount compaction.
__global__ __launch_bounds__(256) void k_dedup(unsigned* __restrict__ cnt,
                                               unsigned short* __restrict__ cols) {
    __shared__ unsigned short ls[4][MAXDEG];
    const int wv = threadIdx.x >> 6, lane = threadIdx.x & 63;
    const int r = blockIdx.x * 4 + wv;
    const int kraw = min((int)cnt[r], MAXDEG);
    unsigned short* cl = &cols[r * MAXDEG];
    for (int i = lane; i < kraw; i += 64) ls[wv][i] = cl[i];
    // same-wave LDS write->read: compiler inserts lgkmcnt wait (may-alias)
    int c0 = (lane < kraw) ? (int)ls[wv][lane] : -1;
    int dup0 = 0;
    for (int j = 0; j < lane && j < kraw; ++j)
        dup0 |= ((int)ls[wv][j] == c0);
    unsigned long long m0 = __ballot(lane < kraw && !dup0);
    unsigned long long below = (1ULL << lane) - 1ULL;
    unsigned total = __popcll(m0);
    if (lane < kraw && !dup0)
        cl[__popcll(m0 & below)] = (unsigned short)c0;
    if (kraw > 64) {                       // wave-uniform, rare
        int i1 = lane + 64;
        int c1 = (i1 < kraw) ? (int)ls[wv][i1] : -1;
        int dup1 = 0;
        for (int j = 0; j < i1 && j < kraw; ++j)
            dup1 |= ((int)ls[wv][j] == c1);
        unsigned long long m1 = __ballot(i1 < kraw && !dup1);
        if (i1 < kraw && !dup1)
            cl[total + __popcll(m1 & below)] = (unsigned short)c1;
        total += __popcll(m1);
    }
    if (lane == 0) cnt[r] = total;
}

// K2: Pd[m][l] = dis_m * (W_g @ ne[m])_l (bf16); uvec = {W_g@Wsp0, W_g@Wsp1, W_g@b_sp}
__global__ __launch_bounds__(256) void k_prep(const float* __restrict__ ne,
                                              const float* __restrict__ W_g,
                                              const float* __restrict__ W_sp,
                                              const float* __restrict__ b_sp,
                                              const unsigned* __restrict__ cnt,
                                              __hip_bfloat16* __restrict__ Pd,
                                              float* __restrict__ uvec) {
    __shared__ float wg[H * (H + 1)];
    int tid = threadIdx.x;
    for (int i = tid; i < H * H; i += 256)
        wg[(i >> 6) * (H + 1) + (i & 63)] = W_g[i];
    __syncthreads();
    const int l = tid & 63, w = tid >> 6;
    float wr[H];
#pragma unroll
    for (int k = 0; k < H; ++k) wr[k] = wg[l * (H + 1) + k];

    if (blockIdx.x == 0 && w == 0) {
        float v0 = W_sp[l * 2 + 0], v1 = W_sp[l * 2 + 1], vb = b_sp[l];
        float a0 = 0.f, a1 = 0.f, a2 = 0.f;
#pragma unroll
        for (int k = 0; k < H; ++k) {
            a0 = fmaf(wr[k], __shfl(v0, k, 64), a0);
            a1 = fmaf(wr[k], __shfl(v1, k, 64), a1);
            a2 = fmaf(wr[k], __shfl(vb, k, 64), a2);
        }
        uvec[l] = a0; uvec[64 + l] = a1; uvec[128 + l] = a2;
    }

#pragma unroll
    for (int it = 0; it < 4; ++it) {
        int m = (blockIdx.x * 4 + w) * 4 + it;
        float nev = ne[m * H + l];
        float c0 = 0.f, c1 = 0.f, c2 = 0.f, c3 = 0.f;
#pragma unroll
        for (int k = 0; k < H; k += 4) {
            c0 = fmaf(wr[k + 0], __shfl(nev, k + 0, 64), c0);
            c1 = fmaf(wr[k + 1], __shfl(nev, k + 1, 64), c1);
            c2 = fmaf(wr[k + 2], __shfl(nev, k + 2, 64), c2);
            c3 = fmaf(wr[k + 3], __shfl(nev, k + 3, 64), c3);
        }
        float dis = rsqrtf((float)(cnt[m] + 1u));
        Pd[m * H + l] = __float2bfloat16(dis * ((c0 + c1) + (c2 + c3)));
    }
}

// K3: xd[m][0..7]=dis*x0_b, [8..15]=dis*x1_b, [16]=dis, [17..24]=pmask_b, rest 0.
__global__ __launch_bounds__(256) void k_xd(const float* __restrict__ x,
                                            const float* __restrict__ pmask,
                                            const unsigned* __restrict__ cnt,
                                            float* __restrict__ xd,
                                            float* __restrict__ nlacc) {
    int m = blockIdx.x * blockDim.x + threadIdx.x;
    float dis = rsqrtf((float)(cnt[m] + 1u));
    float row[32];
#pragma unroll
    for (int j = 0; j < 32; ++j) row[j] = 0.f;
    row[16] = dis;
#pragma unroll
    for (int b = 0; b < B; ++b) {
        float2 xv = ((const float2*)x)[b * N + m];
        row[b]      = dis * xv.x;
        row[8 + b]  = dis * xv.y;
        row[17 + b] = pmask[b * N + m];
        float s = xv.x;
        for (int off = 32; off; off >>= 1) s += __shfl_down(s, off, 64);
        if ((threadIdx.x & 63) == 0) atomicAdd(&nlacc[b], s);
    }
    float4* dst = (float4*)&xd[m * 32];
#pragma unroll
    for (int j = 0; j < 8; ++j)
        dst[j] = make_float4(row[4 * j], row[4 * j + 1], row[4 * j + 2], row[4 * j + 3]);
}

// K4: batch-collapsed sparse row-gather + z reconstruction + all reductions.
__global__ __launch_bounds__(256) void k_spmm(const unsigned short* __restrict__ Pd,
                                              const float* __restrict__ xd,
                                              const unsigned* __restrict__ cnt,
                                              const unsigned short* __restrict__ cols,
                                              const float* __restrict__ uvec,
                                              const float* __restrict__ b_g,
                                              const int* __restrict__ target,
                                              float* __restrict__ wr_,
                                              float* __restrict__ pr_,
                                              float* __restrict__ tgt) {
    const int lane = threadIdx.x & 63;
    const int wv = threadIdx.x >> 6;
    const int wid = blockIdx.x * 4 + wv;
    const float u0 = uvec[lane], u1 = uvec[64 + lane], ub = uvec[128 + lane];
    const float bg = b_g[lane];
    int tg[B];
#pragma unroll
    for (int b = 0; b < B; ++b) tg[b] = target[b];
    float wa[B], pa[B];
#pragma unroll
    for (int b = 0; b < B; ++b) { wa[b] = 0.f; pa[b] = 0.f; }

    for (int i = 0; i < RPW; ++i) {
        const int r = wid * RPW + i;
        float rloc = xd[r * 32 + (lane & 31)];
        float sp = bf2f(Pd[r * H + lane]);          // eye term
        float sx = rloc;
        const int kc = min((int)cnt[r], MAXDEG);
        const unsigned short* cl = &cols[r * MAXDEG];
#pragma unroll 4
        for (int k = 0; k < kc; ++k) {
            int c = (int)cl[k];
            sp += bf2f(Pd[c * H + lane]);
            sx += xd[c * 32 + (lane & 31)];
        }
        const float dis_r = __shfl(rloc, 16, 64);
        const float rdis = 1.0f / dis_r;
        const float sd = __shfl(sx, 16, 64);
        const float base = fmaf(sd, ub, sp);
#pragma unroll
        for (int b = 0; b < B; ++b) {
            float sx0 = __shfl(sx, b, 64);
            float sx1 = __shfl(sx, 8 + b, 64);
            float sc  = __shfl(rloc, 8 + b, 64) * rdis;   // score = x1
            float mk  = __shfl(rloc, 17 + b, 64);
            float v = fmaf(sx0, u0, fmaf(sx1, u1, base));
            float z = fmaxf(fmaf(dis_r, v, bg), 0.f);
            wa[b] = fmaf(z, sc, wa[b]);
            float spl = z + __logf(1.f + __expf(-z));     // softplus, z>=0 stable
            pa[b] = fmaf(spl, mk, pa[b]);
            if (r == tg[b]) tgt[b * H + lane] = z;
        }
    }
    const int rep = wid & (REPS - 1);
#pragma unroll
    for (int b = 0; b < B; ++b) {
        atomicAdd(&wr_[(rep * B + b) * H + lane], wa[b]);
        atomicAdd(&pr_[(rep * B + b) * H + lane], pa[b]);
    }
}

// K5: reduce replicas, per-batch dots, sigmoid
__global__ __launch_bounds__(512) void k_final(const float* __restrict__ wr_,
                                               const float* __restrict__ pr_,
                                               const float* __restrict__ nlacc,
                                               const float* __restrict__ tgt,
                                               const float* __restrict__ W_d,
                                               const float* __restrict__ b_d,
                                               const float* __restrict__ W_a,
                                               const float* __restrict__ b_a,
                                               const float* __restrict__ prereq_w,
                                               float* __restrict__ out) {
    int tid = threadIdx.x, b = tid >> 6, h = tid & 63;
    float ws = 0.f, ps = 0.f;
#pragma unroll 8
    for (int rep = 0; rep < REPS; ++rep) {
        ws += wr_[(rep * B + b) * H + h];
        ps += pr_[(rep * B + b) * H + h];
    }
    float nl = fmaxf(nlacc[b], 1.0f);
    float ap = (ws / nl) * W_a[h];
    float dp = tgt[b * H + h] * W_d[h];
    float pp = ps;
    for (int off = 32; off; off >>= 1) {
        ap += __shfl_down(ap, off, 64);
        dp += __shfl_down(dp, off, 64);
        pp += __shfl_down(pp, off, 64);
    }
    if (h == 0) {
        float ability    = ap + b_a[0];
        float difficulty = dp + b_d[0];
        float preq       = fabsf(prereq_w[0]) * (pp * (1.0f / (float)H));
        float gap  = ability - difficulty + preq;
        float prob = 1.0f / (1.0f + __expf(-gap));
        out[b]     = prob;
        out[B + b] = gap;
    }
}

extern "C" void kernel_launch(void* const* d_in, const int* in_sizes, int n_in,
                              void* d_out, int out_size, void* d_ws, size_t ws_size,
                              hipStream_t stream) {
    const float* x        = (const float*)d_in[0];
    const int*   ei       = (const int*)d_in[1];
    const int*   target   = (const int*)d_in[2];
    const float* pmask    = (const float*)d_in[3];
    const float* node_emb = (const float*)d_in[4];
    const float* W_sp     = (const float*)d_in[5];
    const float* b_sp     = (const float*)d_in[6];
    const float* W_g      = (const float*)d_in[7];
    const float* b_g      = (const float*)d_in[8];
    const float* W_d      = (const float*)d_in[9];
    const float* b_d      = (const float*)d_in[10];
    const float* W_a      = (const float*)d_in[11];
    const float* b_a      = (const float*)d_in[12];
    const float* prereq_w = (const float*)d_in[13];

    const int nE = in_sizes[1] / 2;

    char* ws = (char*)d_ws;
    unsigned*        cnt  = (unsigned*)(ws + OFF_CNT);
    float*           wr_  = (float*)(ws + OFF_WR);
    float*           pr_  = (float*)(ws + OFF_PR);
    float*           nlac = (float*)(ws + OFF_NL);
    unsigned short*  cols = (unsigned short*)(ws + OFF_COLS);
    float*           tgt  = (float*)(ws + OFF_TGT);
    float*           uvec = (float*)(ws + OFF_UV);
    float*           xd   = (float*)(ws + OFF_XD);
    __hip_bfloat16*  Pd   = (__hip_bfloat16*)(ws + OFF_PD);

    // zero accumulators ourselves (runtime fill kernel measured ~40us)
    k_zero<<<(unsigned)(ZERO_END / 16 + 255) / 256, 256, 0, stream>>>((float4*)ws);

    k_edges<<<(nE + 255) / 256, 256, 0, stream>>>(ei, nE, cnt, cols);
    k_dedup<<<N / 4, 256, 0, stream>>>(cnt, cols);
    k_prep<<<N / 16, 256, 0, stream>>>(node_emb, W_g, W_sp, b_sp, cnt, Pd, uvec);
    k_xd<<<N / 256, 256, 0, stream>>>(x, pmask, cnt, xd, nlac);
    k_spmm<<<N / (4 * RPW), 256, 0, stream>>>((const unsigned short*)Pd, xd, cnt, cols,
                                              uvec, b_g, target, wr_, pr_, tgt);
    k_final<<<1, 512, 0, stream>>>(wr_, pr_, nlac, tgt, W_d, b_d, W_a, b_a,
                                   prereq_w, (float*)d_out);
}

// Round 7
// 79.162 us; speedup vs baseline: 2.3936x; 1.0291x over previous
//
#include <hip/hip_runtime.h>
#include <hip/hip_bf16.h>
#include <math.h>

#define N 8192
#define H 64
#define B 8
#define MAXDEG 128
#define REPS 32
#define RPW 2            // rows per wave in k_spmm

// ---- workspace layout (bytes) ----
// zeroed every call by k_zero: [0, ZERO_END)
#define OFF_MASK 0ULL            // 8192*8192/8 = 8,388,608
#define OFF_CNT  8388608ULL      // 8192 u32 = 32768
#define OFF_WR   8421376ULL      // REPS*8*64 f32 = 65536
#define OFF_PR   8486912ULL      // 65536
#define OFF_NL   8552448ULL      // 8 f32 + pad = 64
#define ZERO_END 8552512ULL      // /16 = 534,532 float4
// not zeroed:
#define OFF_COLS 8552512ULL      // 8192*128 u16 = 2,097,152
#define OFF_TGT  10649664ULL     // 512 f32 = 2048
#define OFF_UV   10651712ULL     // 3*64 f32 = 768
#define OFF_XD   10652480ULL     // 8192*32 f32 = 1,048,576 (16B aligned)
#define OFF_PD   11701056ULL     // 8192*64 bf16 = 1,048,576
// end ~12.75 MB

__device__ __forceinline__ float bf2f(unsigned short u) {
    return __uint_as_float(((unsigned)u) << 16);
}

// K0: fast zero of mask+cnt+accumulators (runtime fill kernel was 215 GB/s)
__global__ __launch_bounds__(256) void k_zero(float4* __restrict__ p) {
    unsigned i = blockIdx.x * 256u + threadIdx.x;
    if (i < (unsigned)(ZERO_END / 16))
        p[i] = make_float4(0.f, 0.f, 0.f, 0.f);
}

// K1: one-pass dedup via N^2 bitmask; distinct out-degree; padded u16 col lists
__global__ __launch_bounds__(256) void k_edges(const int* __restrict__ ei, int nE,
                                               unsigned* __restrict__ bits,
                                               unsigned* __restrict__ cnt,
                                               unsigned short* __restrict__ cols) {
    int e = blockIdx.x * blockDim.x + threadIdx.x;
    if (e >= nE) return;
    int r = ei[e];
    int c = ei[nE + e];
    unsigned bitidx = (unsigned)r * (unsigned)N + (unsigned)c;   // < 2^26
    unsigned bit = 1u << (bitidx & 31u);
    unsigned old = atomicOr(&bits[bitidx >> 5], bit);
    if (!(old & bit)) {
        unsigned k = atomicAdd(&cnt[r], 1u);
        if (k < MAXDEG) cols[r * MAXDEG + k] = (unsigned short)c;
    }
}

// K2: fused prep (Pd = dis * ne@W_g^T, bf16) + uvec + xd.
// Blocks [0,512): prep 16 nodes each. W_g rows in VGPRs (loaded once via
// padded LDS, conflict-free (l+k)%32), ne rows in LDS, inner loop =
// ds_read_b128 broadcast + pure VALU FMA (~5x fewer DS ops than shfl form).
// Blocks [512,544): xd (256 nodes each) + n_learned partials.
__global__ __launch_bounds__(256) void k_prepxd(const float* __restrict__ ne,
                                                const float* __restrict__ W_g,
                                                const float* __restrict__ W_sp,
                                                const float* __restrict__ b_sp,
                                                const float* __restrict__ x,
                                                const float* __restrict__ pmask,
                                                const unsigned* __restrict__ cnt,
                                                __hip_bfloat16* __restrict__ Pd,
                                                float* __restrict__ uvec,
                                                float* __restrict__ xd,
                                                float* __restrict__ nlacc) {
    __shared__ float wgs[H * 65];                 // padded: read bank (l+k)%32
    __shared__ __align__(16) float hv[16 * H];    // 16 ne rows
    const int tid = threadIdx.x, lane = tid & 63, wv = tid >> 6;
    const int bid = blockIdx.x;

    if (bid < 512) {
        // ---- stage W_g (coalesced global, 2-way-free LDS writes) ----
        for (int e = tid; e < H * H; e += 256)
            wgs[(e >> 6) * 65 + (e & 63)] = W_g[e];
        // ---- stage 16 ne rows ----
        const float* nebase = ne + (size_t)bid * 16 * H;
        for (int j = 0; j < 4; ++j) {
            int e = tid + j * 256;
            hv[e] = nebase[e];
        }
        __syncthreads();
        // ---- W_g row 'lane' into VGPRs (conflict-free scalar reads) ----
        float wr[H];
#pragma unroll
        for (int k = 0; k < H; ++k) wr[k] = wgs[lane * 65 + k];

        // uvec = {W_g@Wsp0, W_g@Wsp1, W_g@b_sp} (block 0, wave 0 only)
        if (bid == 0 && wv == 0) {
            float v0 = W_sp[lane * 2 + 0], v1 = W_sp[lane * 2 + 1], vb = b_sp[lane];
            float a0 = 0.f, a1 = 0.f, a2 = 0.f;
#pragma unroll
            for (int k = 0; k < H; ++k) {
                a0 = fmaf(wr[k], __shfl(v0, k, 64), a0);
                a1 = fmaf(wr[k], __shfl(v1, k, 64), a1);
                a2 = fmaf(wr[k], __shfl(vb, k, 64), a2);
            }
            uvec[lane] = a0; uvec[64 + lane] = a1; uvec[128 + lane] = a2;
        }

        // ---- 4 nodes per wave: broadcast b128 reads + VALU FMA ----
        for (int ii = 0; ii < 4; ++ii) {
            const int node = wv * 4 + ii;
            const int m = bid * 16 + node;
            const float4* h4p = (const float4*)&hv[node * H];
            float acc = 0.f;
#pragma unroll
            for (int kk = 0; kk < 16; ++kk) {
                float4 h4 = h4p[kk];
                acc = fmaf(wr[4 * kk + 0], h4.x, acc);
                acc = fmaf(wr[4 * kk + 1], h4.y, acc);
                acc = fmaf(wr[4 * kk + 2], h4.z, acc);
                acc = fmaf(wr[4 * kk + 3], h4.w, acc);
            }
            float dis = rsqrtf((float)(cnt[m] + 1u));
            Pd[m * H + lane] = __float2bfloat16(dis * acc);
        }
    } else {
        // ---- xd: m in [0,8192), one node per thread ----
        const int m = (bid - 512) * 256 + tid;
        float dis = rsqrtf((float)(cnt[m] + 1u));
        float row[32];
#pragma unroll
        for (int j = 0; j < 32; ++j) row[j] = 0.f;
        row[16] = dis;
#pragma unroll
        for (int b = 0; b < B; ++b) {
            float2 xv = ((const float2*)x)[b * N + m];
            row[b]      = dis * xv.x;
            row[8 + b]  = dis * xv.y;
            row[17 + b] = pmask[b * N + m];
            float s = xv.x;
            for (int off = 32; off; off >>= 1) s += __shfl_down(s, off, 64);
            if (lane == 0) atomicAdd(&nlacc[b], s);
        }
        float4* dst = (float4*)&xd[m * 32];
#pragma unroll
        for (int j = 0; j < 8; ++j)
            dst[j] = make_float4(row[4 * j], row[4 * j + 1], row[4 * j + 2], row[4 * j + 3]);
    }
}

// K3: batch-collapsed sparse row-gather + z reconstruction + all reductions.
__global__ __launch_bounds__(256) void k_spmm(const unsigned short* __restrict__ Pd,
                                              const float* __restrict__ xd,
                                              const unsigned* __restrict__ cnt,
                                              const unsigned short* __restrict__ cols,
                                              const float* __restrict__ uvec,
                                              const float* __restrict__ b_g,
                                              const int* __restrict__ target,
                                              float* __restrict__ wr_,
                                              float* __restrict__ pr_,
                                              float* __restrict__ tgt) {
    const int lane = threadIdx.x & 63;
    const int wv = threadIdx.x >> 6;
    const int wid = blockIdx.x * 4 + wv;
    const float u0 = uvec[lane], u1 = uvec[64 + lane], ub = uvec[128 + lane];
    const float bg = b_g[lane];
    int tg[B];
#pragma unroll
    for (int b = 0; b < B; ++b) tg[b] = target[b];
    float wa[B], pa[B];
#pragma unroll
    for (int b = 0; b < B; ++b) { wa[b] = 0.f; pa[b] = 0.f; }

    for (int i = 0; i < RPW; ++i) {
        const int r = wid * RPW + i;
        float rloc = xd[r * 32 + (lane & 31)];
        float sp = bf2f(Pd[r * H + lane]);          // eye term (pre-scaled)
        float sx = rloc;
        const int kc = min((int)cnt[r], MAXDEG);
        const unsigned short* cl = &cols[r * MAXDEG];
#pragma unroll 4
        for (int k = 0; k < kc; ++k) {
            int c = (int)cl[k];
            sp += bf2f(Pd[c * H + lane]);
            sx += xd[c * 32 + (lane & 31)];
        }
        const float dis_r = __shfl(rloc, 16, 64);
        const float rdis = 1.0f / dis_r;
        const float sd = __shfl(sx, 16, 64);
        const float base = fmaf(sd, ub, sp);
#pragma unroll
        for (int b = 0; b < B; ++b) {
            float sx0 = __shfl(sx, b, 64);
            float sx1 = __shfl(sx, 8 + b, 64);
            float sc  = __shfl(rloc, 8 + b, 64) * rdis;   // score = x1
            float mk  = __shfl(rloc, 17 + b, 64);
            float v = fmaf(sx0, u0, fmaf(sx1, u1, base));
            float z = fmaxf(fmaf(dis_r, v, bg), 0.f);
            wa[b] = fmaf(z, sc, wa[b]);
            float spl = z + __logf(1.f + __expf(-z));     // softplus, z>=0 stable
            pa[b] = fmaf(spl, mk, pa[b]);
            if (r == tg[b]) tgt[b * H + lane] = z;
        }
    }
    const int rep = wid & (REPS - 1);
#pragma unroll
    for (int b = 0; b < B; ++b) {
        atomicAdd(&wr_[(rep * B + b) * H + lane], wa[b]);
        atomicAdd(&pr_[(rep * B + b) * H + lane], pa[b]);
    }
}

// K4: reduce replicas, per-batch dots, sigmoid
__global__ __launch_bounds__(512) void k_final(const float* __restrict__ wr_,
                                               const float* __restrict__ pr_,
                                               const float* __restrict__ nlacc,
                                               const float* __restrict__ tgt,
                                               const float* __restrict__ W_d,
                                               const float* __restrict__ b_d,
                                               const float* __restrict__ W_a,
                                               const float* __restrict__ b_a,
                                               const float* __restrict__ prereq_w,
                                               float* __restrict__ out) {
    int tid = threadIdx.x, b = tid >> 6, h = tid & 63;
    float ws = 0.f, ps = 0.f;
#pragma unroll 8
    for (int rep = 0; rep < REPS; ++rep) {
        ws += wr_[(rep * B + b) * H + h];
        ps += pr_[(rep * B + b) * H + h];
    }
    float nl = fmaxf(nlacc[b], 1.0f);
    float ap = (ws / nl) * W_a[h];
    float dp = tgt[b * H + h] * W_d[h];
    float pp = ps;
    for (int off = 32; off; off >>= 1) {
        ap += __shfl_down(ap, off, 64);
        dp += __shfl_down(dp, off, 64);
        pp += __shfl_down(pp, off, 64);
    }
    if (h == 0) {
        float ability    = ap + b_a[0];
        float difficulty = dp + b_d[0];
        float preq       = fabsf(prereq_w[0]) * (pp * (1.0f / (float)H));
        float gap  = ability - difficulty + preq;
        float prob = 1.0f / (1.0f + __expf(-gap));
        out[b]     = prob;
        out[B + b] = gap;
    }
}

extern "C" void kernel_launch(void* const* d_in, const int* in_sizes, int n_in,
                              void* d_out, int out_size, void* d_ws, size_t ws_size,
                              hipStream_t stream) {
    const float* x        = (const float*)d_in[0];
    const int*   ei       = (const int*)d_in[1];
    const int*   target   = (const int*)d_in[2];
    const float* pmask    = (const float*)d_in[3];
    const float* node_emb = (const float*)d_in[4];
    const float* W_sp     = (const float*)d_in[5];
    const float* b_sp     = (const float*)d_in[6];
    const float* W_g      = (const float*)d_in[7];
    const float* b_g      = (const float*)d_in[8];
    const float* W_d      = (const float*)d_in[9];
    const float* b_d      = (const float*)d_in[10];
    const float* W_a      = (const float*)d_in[11];
    const float* b_a      = (const float*)d_in[12];
    const float* prereq_w = (const float*)d_in[13];

    const int nE = in_sizes[1] / 2;

    char* ws = (char*)d_ws;
    unsigned*        bits = (unsigned*)(ws + OFF_MASK);
    unsigned*        cnt  = (unsigned*)(ws + OFF_CNT);
    float*           wr_  = (float*)(ws + OFF_WR);
    float*           pr_  = (float*)(ws + OFF_PR);
    float*           nlac = (float*)(ws + OFF_NL);
    unsigned short*  cols = (unsigned short*)(ws + OFF_COLS);
    float*           tgt  = (float*)(ws + OFF_TGT);
    float*           uvec = (float*)(ws + OFF_UV);
    float*           xd   = (float*)(ws + OFF_XD);
    __hip_bfloat16*  Pd   = (__hip_bfloat16*)(ws + OFF_PD);

    // ws poisoned 0xAA once, never re-poisoned between replays -> zero every call
    k_zero<<<(unsigned)(ZERO_END / 16 + 255) / 256, 256, 0, stream>>>((float4*)ws);
    k_edges<<<(nE + 255) / 256, 256, 0, stream>>>(ei, nE, bits, cnt, cols);
    k_prepxd<<<544, 256, 0, stream>>>(node_emb, W_g, W_sp, b_sp, x, pmask, cnt,
                                      Pd, uvec, xd, nlac);
    k_spmm<<<N / (4 * RPW), 256, 0, stream>>>((const unsigned short*)Pd, xd, cnt, cols,
                                              uvec, b_g, target, wr_, pr_, tgt);
    k_final<<<1, 512, 0, stream>>>(wr_, pr_, nlac, tgt, W_d, b_d, W_a, b_a,
                                   prereq_w, (float*)d_out);
}